// Round 13
// baseline (191.751 us; speedup 1.0000x reference)
//
#include <hip/hip_runtime.h>
#include <hip/hip_bf16.h>

typedef short bf8 __attribute__((ext_vector_type(8)));   // 8 bf16 (4 VGPRs)
typedef float f4 __attribute__((ext_vector_type(4)));
typedef const __attribute__((address_space(1))) void* gvp;
typedef __attribute__((address_space(3))) void* lvp;

#define S_LEN 4096
#define H_DIM 1024
#define D_DIM 512
#define B_DIM 16
#define OUT_BASE ((size_t)B_DIM * S_LEN * H_DIM)

// float -> bf16 bits, round-to-nearest-even
static __device__ __forceinline__ unsigned short f2bf(float f) {
    union { float f; unsigned int u; } c; c.f = f;
    unsigned int u = c.u;
    return (unsigned short)((u + 0x7FFFu + ((u >> 16) & 1u)) >> 16);
}

// cW1 [K=1024][N=512] f32 -> wT[n][chunk 0..31][slot 0..3] bf16 (pitch 2048 B),
// PRE-SWIZZLED: slot sl holds k-slot j = sl ^ ((n>>1)&3). GEMM's linear global_load_lds
// + swizzled ds_read (slot = lg ^ ((la>>1)&3)) recovers k-slot lg; 2-way-bank (free).
__global__ __launch_bounds__(256) void prep_transpose(const float* __restrict__ cW1,
                                                      unsigned short* __restrict__ wT) {
    __shared__ float tile[64][68];
    const int kt = blockIdx.x >> 3;   // 16 tiles of 64 k
    const int nt = blockIdx.x & 7;    // 8 tiles of 64 n
    const int tr = threadIdx.x >> 4;
    const int tc = threadIdx.x & 15;
#pragma unroll
    for (int i = 0; i < 4; ++i) {
        const f4 v = *(const f4*)(cW1 + (size_t)(kt * 64 + i * 16 + tr) * D_DIM + nt * 64 + tc * 4);
        tile[i * 16 + tr][tc * 4 + 0] = v.x;
        tile[i * 16 + tr][tc * 4 + 1] = v.y;
        tile[i * 16 + tr][tc * 4 + 2] = v.z;
        tile[i * 16 + tr][tc * 4 + 3] = v.w;
    }
    __syncthreads();
    const int n_local = threadIdx.x & 63;
    const int q = threadIdx.x >> 6;        // slot 0..3
    const int n = nt * 64 + n_local;
    const int j = q ^ ((n >> 1) & 3);      // data k-slot stored at slot q
    char* wTb = (char*)wT;
#pragma unroll
    for (int c_local = 0; c_local < 2; ++c_local) {   // two 32-k chunks per 64k tile
        const int k0 = c_local * 32 + j * 8;
        bf8 pk;
#pragma unroll
        for (int i = 0; i < 8; ++i) pk[i] = (short)f2bf(tile[k0 + i][n_local]);
        *(bf8*)(wTb + (size_t)n * 2048 + (kt * 2 + c_local) * 64 + q * 16) = pk;
    }
}

// Fused stream+GEMM, depth-2 pipeline. M=128 (one b, 128 s) x N=512, BK=32 (32 chunks),
// 8 waves (2M x 4N), acc[4][8]=128 AGPR, 1 block/CU. B TRIPLE-buffered (96 KB), issued
// 2 chunks ahead; A dbuf (16 KB) reg-staged depth-2; out-copy fused with PLAIN stores
// (L2-acked, L2/L3-merged — nt caused HBM acks + amplification). Queue order per iter
// guarantees no wait ever touches ops younger than its target (derived retire sets).
__global__ __launch_bounds__(512, 2) void comp_gemm_kernel(
    const float* __restrict__ states,
    const unsigned short* __restrict__ wT,
    const float* __restrict__ cb1,
    const float* __restrict__ cW2,
    const float* __restrict__ cb2,
    float* __restrict__ out,
    float* __restrict__ part_ws) {
    __shared__ alignas(16) char lds[114688];  // B [3][512][64] @0 ; A [2][128][64] @98304
    char* ldsB = lds;
    char* ldsA = lds + 98304;

    const int t = threadIdx.x;
    const int lane = t & 63;
    const int wv = t >> 6;                // 0..7
    const int wm = wv >> 2;               // 0..1 : rows [wm*64, +64)
    const int wn = wv & 3;                // 0..3 : cols [wn*128, +128)
    const int la = lane & 15;
    const int lg = lane >> 4;
    const int b = blockIdx.x >> 5;
    const int s0 = (blockIdx.x & 31) * 128;

    // ---- A staging / fused copy-out: (row = t>>2, kq = t&3), 2 f4 = 32 B/thread ----
    const int arow = t >> 2;
    const int kq = t & 3;
    const size_t abase = ((size_t)b * S_LEN + s0 + arow) * H_DIM + kq * 8;
    const float* srcA = states + abase;
    float* dstO = out + abase;
    char* dstA = ldsA + arow * 64 + ((kq ^ (arow & 3) ^ ((arow >> 2) & 3)) * 16);

    // ---- B staging: 4 x global_load_lds(16B/lane)/chunk; linear dest, swizzled src ----
    const char* srcB = (const char*)wT + (size_t)(t >> 2) * 2048 + (t & 3) * 16;
    char* dstB = ldsB + t * 16;

    // ---- fragment read bases ----
    const char* brd = ldsB + (wn * 128 + la) * 64 + ((lg ^ ((la >> 1) & 3)) * 16);
    const char* ard = ldsA + (wm * 64 + la) * 64 + ((lg ^ (la & 3) ^ ((la >> 2) & 3)) * 16);

    f4 acc[4][8];
#pragma unroll
    for (int a = 0; a < 4; ++a)
#pragma unroll
        for (int c = 0; c < 8; ++c) acc[a][c] = f4{0.f, 0.f, 0.f, 0.f};

    auto issueB = [&](int bufi, int ck_) {
#pragma unroll
        for (int i = 0; i < 4; ++i)
            __builtin_amdgcn_global_load_lds((gvp)(srcB + (size_t)i * 128 * 2048 + ck_ * 64),
                                             (lvp)(dstB + bufi * 32768 + i * 8192), 16, 0, 0);
    };
    auto writeA = [&](int bufa, const f4 a0, const f4 a1) {
        bf8 pk;
        pk[0] = (short)f2bf(a0.x); pk[1] = (short)f2bf(a0.y);
        pk[2] = (short)f2bf(a0.z); pk[3] = (short)f2bf(a0.w);
        pk[4] = (short)f2bf(a1.x); pk[5] = (short)f2bf(a1.y);
        pk[6] = (short)f2bf(a1.z); pk[7] = (short)f2bf(a1.w);
        *(bf8*)(dstA + bufa * 8192) = pk;
    };
    auto storeO = [&](int ck_, const f4 a0, const f4 a1) {   // PLAIN stores (L2-acked)
        *(f4*)(dstO + ck_ * 32) = a0;
        *(f4*)(dstO + ck_ * 32 + 4) = a1;
    };

    // ---- prologue: order [ldA0 x2, B0 x4, glA1 x2, st0 x2, B1 x4] ----
    f4 qa0 = *(const f4*)(srcA);
    f4 qa1 = *(const f4*)(srcA + 4);
    issueB(0, 0);
    f4 qn0 = *(const f4*)(srcA + 32);
    f4 qn1 = *(const f4*)(srcA + 36);
    writeA(0, qa0, qa1);                 // waits ldA0 only (oldest)
    storeO(0, qa0, qa1);
    issueB(1, 1);
    // queue: [B0 x4, glA1 x2, st0 x2, B1 x4] -> vmcnt(8) retires exactly B0
    asm volatile("s_waitcnt vmcnt(8) lgkmcnt(0)" ::: "memory");
    __builtin_amdgcn_sched_barrier(0);
    __builtin_amdgcn_s_barrier();
    __builtin_amdgcn_sched_barrier(0);
    qa0 = qn0; qa1 = qn1;

#pragma unroll 1
    for (int ck = 0; ck < 32; ++ck) {
        const int bufc = ck % 3;
        if (ck < 31) {
            // writeA's qa-wait retires [st(ck) x2, glA(ck+1) x2]; leaves B(ck+1) x4 flying
            writeA((ck + 1) & 1, qa0, qa1);
            storeO(ck + 1, qa0, qa1);
            if (ck < 30) {
                qn0 = *(const f4*)(srcA + (ck + 2) * 32);
                qn1 = *(const f4*)(srcA + (ck + 2) * 32 + 4);
                issueB((ck + 2) % 3, ck + 2);
            }
            __builtin_amdgcn_sched_barrier(0);
        }
        // ---- compute chunk ck: A from ldsA[ck&1], B from buf[ck%3] ----
        bf8 af[4];
#pragma unroll
        for (int fr = 0; fr < 4; ++fr)
            af[fr] = *(const bf8*)(ard + (ck & 1) * 8192 + fr * 1024);
#pragma unroll
        for (int fc = 0; fc < 8; ++fc) {
            const bf8 bv = *(const bf8*)(brd + bufc * 32768 + fc * 1024);
#pragma unroll
            for (int fr = 0; fr < 4; ++fr)
                acc[fr][fc] = __builtin_amdgcn_mfma_f32_16x16x32_bf16(af[fr], bv, acc[fr][fc], 0, 0, 0);
        }
        if (ck < 31) {
            // queue: [B(ck+1) x4, st x2, glA x2, B(ck+2) x4] -> vmcnt(8) retires B(ck+1)
            // (ck==30: [B31 x4, st31 x2] -> vmcnt(2))
            if (ck < 30) { asm volatile("s_waitcnt vmcnt(8) lgkmcnt(0)" ::: "memory"); }
            else         { asm volatile("s_waitcnt vmcnt(2) lgkmcnt(0)" ::: "memory"); }
            __builtin_amdgcn_sched_barrier(0);
            __builtin_amdgcn_s_barrier();
            __builtin_amdgcn_sched_barrier(0);
            if (ck < 30) { qa0 = qn0; qa1 = qn1; }
        }
    }

    // ---- epilogue: relu + dot(cW2) + sigmoid/16 -> per-(b,s) partial ----
    float w2v[8], b1v[8];
#pragma unroll
    for (int fc = 0; fc < 8; ++fc) {
        const int d = wn * 128 + fc * 16 + la;
        w2v[fc] = cW2[d];
        b1v[fc] = cb1[d];
    }
    float* part = (float*)lds;   // overlays B-buf0 (last read at ck=30; iter31 reads buf1)
#pragma unroll
    for (int fr = 0; fr < 4; ++fr) {
#pragma unroll
        for (int rg = 0; rg < 4; ++rg) {
            float p = 0.f;
#pragma unroll
            for (int fc = 0; fc < 8; ++fc)
                p += fmaxf(acc[fr][fc][rg] + b1v[fc], 0.f) * w2v[fc];
#pragma unroll
            for (int off = 1; off < 16; off <<= 1)
                p += __shfl_xor(p, off, 64);      // sum over 16 lane-columns (n)
            if (la == 0) part[(wm * 64 + fr * 16 + lg * 4 + rg) * 4 + wn] = p;
        }
    }
    __syncthreads();
    if (t < 128) {
        float sum = cb2[0] + part[t * 4 + 0] + part[t * 4 + 1] + part[t * 4 + 2] + part[t * 4 + 3];
        const float sg = 1.f / (1.f + __expf(-sum));
        part_ws[(size_t)b * S_LEN + s0 + t] = sg * (1.f / 16.f);
    }
}

// comp_mean[s] = sum_b partial[b][s]; steps_used ≡ 1 (rb<=128-t can never make
// trunc(rb/(S-t+1))>=2; negative rb clips to 1); rb_final = 128-4096 = -3968.
__global__ __launch_bounds__(256) void reduce_comp(const float* __restrict__ part_ws,
                                                   float* __restrict__ out) {
    const int s = blockIdx.x * 256 + threadIdx.x;
    float sum = 0.f;
#pragma unroll
    for (int b = 0; b < B_DIM; ++b) sum += part_ws[(size_t)b * S_LEN + s];
    out[OUT_BASE + S_LEN + s] = sum;     // comp_mean
    out[OUT_BASE + s] = 1.0f;            // steps_used
    if (s == 0) out[OUT_BASE + 2 * S_LEN] = -3968.0f;
}

extern "C" void kernel_launch(void* const* d_in, const int* in_sizes, int n_in,
                              void* d_out, int out_size, void* d_ws, size_t ws_size,
                              hipStream_t stream) {
    const float* states = (const float*)d_in[0];
    const float* cW1 = (const float*)d_in[5];
    const float* cb1 = (const float*)d_in[6];
    const float* cW2 = (const float*)d_in[7];
    const float* cb2 = (const float*)d_in[8];
    float* out = (float*)d_out;
    unsigned short* wT = (unsigned short*)d_ws;                 // 1 MB bf16, pre-swizzled
    float* part_ws = (float*)((char*)d_ws + (size_t)D_DIM * H_DIM * 2);  // 256 KB [16][4096]

    hipLaunchKernelGGL(prep_transpose, dim3(128), dim3(256), 0, stream, cW1, wT);
    hipLaunchKernelGGL(comp_gemm_kernel, dim3(512), dim3(512), 0, stream,
                       states, wT, cb1, cW2, cb2, out, part_ws);
    hipLaunchKernelGGL(reduce_comp, dim3(16), dim3(256), 0, stream, part_ws, out);
}

// Round 14
// 165.133 us; speedup vs baseline: 1.1612x; 1.1612x over previous
//
#include <hip/hip_runtime.h>
#include <hip/hip_bf16.h>

typedef short bf8 __attribute__((ext_vector_type(8)));   // 8 bf16 (4 VGPRs)
typedef short bf4 __attribute__((ext_vector_type(4)));   // 4 bf16 (8 B)
typedef float f4 __attribute__((ext_vector_type(4)));
typedef const __attribute__((address_space(1))) void* gvp;
typedef __attribute__((address_space(3))) void* lvp;

#define S_LEN 4096
#define H_DIM 1024
#define D_DIM 512
#define B_DIM 16
#define OUT_BASE ((size_t)B_DIM * S_LEN * H_DIM)

// float -> bf16 bits, round-to-nearest-even
static __device__ __forceinline__ unsigned short f2bf(float f) {
    union { float f; unsigned int u; } c; c.f = f;
    unsigned int u = c.u;
    return (unsigned short)((u + 0x7FFFu + ((u >> 16) & 1u)) >> 16);
}

// cW1 [K=1024][N=512] f32 -> wT[n][chunk 0..31][slot 0..3] bf16 (pitch 2048 B),
// PRE-SWIZZLED: slot sl holds k-slot j = sl ^ ((n>>1)&3). GEMM's linear global_load_lds
// + swizzled ds_read (slot = lg ^ ((la>>1)&3)) recovers k-slot lg; 2-way-bank (free).
__global__ __launch_bounds__(256) void prep_transpose(const float* __restrict__ cW1,
                                                      unsigned short* __restrict__ wT) {
    __shared__ float tile[64][68];
    const int kt = blockIdx.x >> 3;   // 16 tiles of 64 k
    const int nt = blockIdx.x & 7;    // 8 tiles of 64 n
    const int tr = threadIdx.x >> 4;
    const int tc = threadIdx.x & 15;
#pragma unroll
    for (int i = 0; i < 4; ++i) {
        const f4 v = *(const f4*)(cW1 + (size_t)(kt * 64 + i * 16 + tr) * D_DIM + nt * 64 + tc * 4);
        tile[i * 16 + tr][tc * 4 + 0] = v.x;
        tile[i * 16 + tr][tc * 4 + 1] = v.y;
        tile[i * 16 + tr][tc * 4 + 2] = v.z;
        tile[i * 16 + tr][tc * 4 + 3] = v.w;
    }
    __syncthreads();
    const int n_local = threadIdx.x & 63;
    const int q = threadIdx.x >> 6;        // slot 0..3
    const int n = nt * 64 + n_local;
    const int j = q ^ ((n >> 1) & 3);      // data k-slot stored at slot q
    char* wTb = (char*)wT;
#pragma unroll
    for (int c_local = 0; c_local < 2; ++c_local) {   // two 32-k chunks per 64k tile
        const int k0 = c_local * 32 + j * 8;
        bf8 pk;
#pragma unroll
        for (int i = 0; i < 8; ++i) pk[i] = (short)f2bf(tile[k0 + i][n_local]);
        *(bf8*)(wTb + (size_t)n * 2048 + (kt * 2 + c_local) * 64 + q * 16) = pk;
    }
}

// Fused stream+GEMM, depth-2 pipeline (R13 structure), SINGLE CHANGE vs R13:
// out-copy uses NT stores with a per-instruction-DENSE map. Thread (row=t>>2,
// half=t&3) owns floats [half*4,+4) and [16+half*4,+4) of its row-chunk -> each
// wave store instruction covers 16 rows x 64 B with no holes (R12-proven: no
// write amplification), and nt keeps the 268-MB write stream OUT of L2 so the
// L2-resident wT / B-fills aren't evicted (R13's plain stores thrashed L2).
__global__ __launch_bounds__(512, 2) void comp_gemm_kernel(
    const float* __restrict__ states,
    const unsigned short* __restrict__ wT,
    const float* __restrict__ cb1,
    const float* __restrict__ cW2,
    const float* __restrict__ cb2,
    float* __restrict__ out,
    float* __restrict__ part_ws) {
    __shared__ alignas(16) char lds[114688];  // B [3][512][64] @0 ; A [2][128][64] @98304
    char* ldsB = lds;
    char* ldsA = lds + 98304;

    const int t = threadIdx.x;
    const int lane = t & 63;
    const int wv = t >> 6;                // 0..7
    const int wm = wv >> 2;               // 0..1 : rows [wm*64, +64)
    const int wn = wv & 3;                // 0..3 : cols [wn*128, +128)
    const int la = lane & 15;
    const int lg = lane >> 4;
    const int b = blockIdx.x >> 5;
    const int s0 = (blockIdx.x & 31) * 128;

    // ---- A staging / fused copy-out: (row = t>>2, half = t&3); two f4 at +0/+64 B
    // within the row-chunk -> per-instruction footprint = 16 rows x 64 B DENSE ----
    const int arow = t >> 2;
    const int half = t & 3;
    const size_t abase = ((size_t)b * S_LEN + s0 + arow) * H_DIM + half * 4;
    const float* srcA = states + abase;
    float* dstO = out + abase;
    const int ax = (arow & 3) ^ ((arow >> 2) & 3);            // A slot swizzle X(row)
    char* dstA0 = ldsA + arow * 64 + (((half >> 1) ^ ax) * 16 + (half & 1) * 8);
    char* dstA1 = ldsA + arow * 64 + ((((half >> 1) + 2) ^ ax) * 16 + (half & 1) * 8);

    // ---- B staging: 4 x global_load_lds(16B/lane)/chunk; linear dest, swizzled src ----
    const char* srcB = (const char*)wT + (size_t)(t >> 2) * 2048 + (t & 3) * 16;
    char* dstB = ldsB + t * 16;

    // ---- fragment read bases ----
    const char* brd = ldsB + (wn * 128 + la) * 64 + ((lg ^ ((la >> 1) & 3)) * 16);
    const char* ard = ldsA + (wm * 64 + la) * 64 + ((lg ^ (la & 3) ^ ((la >> 2) & 3)) * 16);

    f4 acc[4][8];
#pragma unroll
    for (int a = 0; a < 4; ++a)
#pragma unroll
        for (int c = 0; c < 8; ++c) acc[a][c] = f4{0.f, 0.f, 0.f, 0.f};

    auto issueB = [&](int bufi, int ck_) {
#pragma unroll
        for (int i = 0; i < 4; ++i)
            __builtin_amdgcn_global_load_lds((gvp)(srcB + (size_t)i * 128 * 2048 + ck_ * 64),
                                             (lvp)(dstB + bufi * 32768 + i * 8192), 16, 0, 0);
    };
    auto writeA = [&](int bufa, const f4 a0, const f4 a1) {
        bf4 p0, p1;
        p0[0] = (short)f2bf(a0.x); p0[1] = (short)f2bf(a0.y);
        p0[2] = (short)f2bf(a0.z); p0[3] = (short)f2bf(a0.w);
        p1[0] = (short)f2bf(a1.x); p1[1] = (short)f2bf(a1.y);
        p1[2] = (short)f2bf(a1.z); p1[3] = (short)f2bf(a1.w);
        *(bf4*)(dstA0 + bufa * 8192) = p0;
        *(bf4*)(dstA1 + bufa * 8192) = p1;
    };
    auto storeO = [&](int ck_, const f4 a0, const f4 a1) {    // NT, per-instr dense
        __builtin_nontemporal_store(a0, (f4*)(dstO + ck_ * 32));
        __builtin_nontemporal_store(a1, (f4*)(dstO + ck_ * 32 + 16));
    };

    // ---- prologue: order [ldA0 x2, B0 x4, glA1 x2, st0 x2, B1 x4] ----
    f4 qa0 = *(const f4*)(srcA);
    f4 qa1 = *(const f4*)(srcA + 16);
    issueB(0, 0);
    f4 qn0 = *(const f4*)(srcA + 32);
    f4 qn1 = *(const f4*)(srcA + 48);
    writeA(0, qa0, qa1);                 // waits ldA0 only (oldest)
    storeO(0, qa0, qa1);
    issueB(1, 1);
    // queue: [B0 x4, glA1 x2, st0 x2, B1 x4] -> vmcnt(8) retires exactly B0
    asm volatile("s_waitcnt vmcnt(8) lgkmcnt(0)" ::: "memory");
    __builtin_amdgcn_sched_barrier(0);
    __builtin_amdgcn_s_barrier();
    __builtin_amdgcn_sched_barrier(0);
    qa0 = qn0; qa1 = qn1;

#pragma unroll 1
    for (int ck = 0; ck < 32; ++ck) {
        const int bufc = ck % 3;
        if (ck < 31) {
            // writeA's qa-wait retires [st(ck) x2, glA(ck+1) x2]; leaves B(ck+1) x4 flying
            writeA((ck + 1) & 1, qa0, qa1);
            storeO(ck + 1, qa0, qa1);
            if (ck < 30) {
                qn0 = *(const f4*)(srcA + (ck + 2) * 32);
                qn1 = *(const f4*)(srcA + (ck + 2) * 32 + 16);
                issueB((ck + 2) % 3, ck + 2);
            }
            __builtin_amdgcn_sched_barrier(0);
        }
        // ---- compute chunk ck: A from ldsA[ck&1], B from buf[ck%3] ----
        bf8 af[4];
#pragma unroll
        for (int fr = 0; fr < 4; ++fr)
            af[fr] = *(const bf8*)(ard + (ck & 1) * 8192 + fr * 1024);
#pragma unroll
        for (int fc = 0; fc < 8; ++fc) {
            const bf8 bv = *(const bf8*)(brd + bufc * 32768 + fc * 1024);
#pragma unroll
            for (int fr = 0; fr < 4; ++fr)
                acc[fr][fc] = __builtin_amdgcn_mfma_f32_16x16x32_bf16(af[fr], bv, acc[fr][fc], 0, 0, 0);
        }
        if (ck < 31) {
            // queue: [B(ck+1) x4, st x2, glA x2, B(ck+2) x4] -> vmcnt(8) retires B(ck+1)
            // (ck==30: [B31 x4, st31 x2] -> vmcnt(2))
            if (ck < 30) { asm volatile("s_waitcnt vmcnt(8) lgkmcnt(0)" ::: "memory"); }
            else         { asm volatile("s_waitcnt vmcnt(2) lgkmcnt(0)" ::: "memory"); }
            __builtin_amdgcn_sched_barrier(0);
            __builtin_amdgcn_s_barrier();
            __builtin_amdgcn_sched_barrier(0);
            if (ck < 30) { qa0 = qn0; qa1 = qn1; }
        }
    }

    // ---- epilogue: relu + dot(cW2) + sigmoid/16 -> per-(b,s) partial ----
    float w2v[8], b1v[8];
#pragma unroll
    for (int fc = 0; fc < 8; ++fc) {
        const int d = wn * 128 + fc * 16 + la;
        w2v[fc] = cW2[d];
        b1v[fc] = cb1[d];
    }
    float* part = (float*)lds;   // overlays B-buf0 (last read at ck=30; iter31 reads buf1)
#pragma unroll
    for (int fr = 0; fr < 4; ++fr) {
#pragma unroll
        for (int rg = 0; rg < 4; ++rg) {
            float p = 0.f;
#pragma unroll
            for (int fc = 0; fc < 8; ++fc)
                p += fmaxf(acc[fr][fc][rg] + b1v[fc], 0.f) * w2v[fc];
#pragma unroll
            for (int off = 1; off < 16; off <<= 1)
                p += __shfl_xor(p, off, 64);      // sum over 16 lane-columns (n)
            if (la == 0) part[(wm * 64 + fr * 16 + lg * 4 + rg) * 4 + wn] = p;
        }
    }
    __syncthreads();
    if (t < 128) {
        float sum = cb2[0] + part[t * 4 + 0] + part[t * 4 + 1] + part[t * 4 + 2] + part[t * 4 + 3];
        const float sg = 1.f / (1.f + __expf(-sum));
        part_ws[(size_t)b * S_LEN + s0 + t] = sg * (1.f / 16.f);
    }
}

// comp_mean[s] = sum_b partial[b][s]; steps_used ≡ 1 (rb<=128-t can never make
// trunc(rb/(S-t+1))>=2; negative rb clips to 1); rb_final = 128-4096 = -3968.
__global__ __launch_bounds__(256) void reduce_comp(const float* __restrict__ part_ws,
                                                   float* __restrict__ out) {
    const int s = blockIdx.x * 256 + threadIdx.x;
    float sum = 0.f;
#pragma unroll
    for (int b = 0; b < B_DIM; ++b) sum += part_ws[(size_t)b * S_LEN + s];
    out[OUT_BASE + S_LEN + s] = sum;     // comp_mean
    out[OUT_BASE + s] = 1.0f;            // steps_used
    if (s == 0) out[OUT_BASE + 2 * S_LEN] = -3968.0f;
}

extern "C" void kernel_launch(void* const* d_in, const int* in_sizes, int n_in,
                              void* d_out, int out_size, void* d_ws, size_t ws_size,
                              hipStream_t stream) {
    const float* states = (const float*)d_in[0];
    const float* cW1 = (const float*)d_in[5];
    const float* cb1 = (const float*)d_in[6];
    const float* cW2 = (const float*)d_in[7];
    const float* cb2 = (const float*)d_in[8];
    float* out = (float*)d_out;
    unsigned short* wT = (unsigned short*)d_ws;                 // 1 MB bf16, pre-swizzled
    float* part_ws = (float*)((char*)d_ws + (size_t)D_DIM * H_DIM * 2);  // 256 KB [16][4096]

    hipLaunchKernelGGL(prep_transpose, dim3(128), dim3(256), 0, stream, cW1, wT);
    hipLaunchKernelGGL(comp_gemm_kernel, dim3(512), dim3(512), 0, stream,
                       states, wT, cb1, cW2, cb2, out, part_ws);
    hipLaunchKernelGGL(reduce_comp, dim3(16), dim3(256), 0, stream, part_ws, out);
}